// Round 9
// baseline (320.594 us; speedup 1.0000x reference)
//
#include <hip/hip_runtime.h>
#include <math.h>

// ============================================================================
// R9 — DIAGNOSTIC ROUND 2 (asymmetric amplification). edgeA+edgeB launched
// x5 (idempotent); score/topk/gather x1. R9 - R7 = 4*(a+b) + 8c isolates the
// edge-phase cost that rocprof can't show (harness fills own the top-5).
// Kernel code IDENTICAL to R7 (verified: passed, absmax 128, 6 passes).
// ============================================================================

// Problem constants (match reference)
#define BGRAPH 64
#define N_PER  1024
#define KSEL   512
#define NTOT   65536       // BGRAPH * N_PER
#define EDG    2097152
#define FIN    256
#define FE     16

// d_out flat layout (float32 elements), reference tuple order:
#define OFF_XOUT   0
#define OFF_EI     8388608
#define OFF_EA     12582912
#define OFF_BATCH  46137344
#define OFF_PERM   46170112
#define OFF_SCORE  46202880
#define OFF_EMASK  46268416

// d_ws layout: [0,256KB) node_map (int[65536]); [256KB,768KB) dots (double[65536])
#define WS_DOTS_OFF 65536   // in ints

// ---------------------------------------------------------------------------
// Kernel 1 (FROZEN): z = dot(x,W)+b in f64 rank key; value via f32 tanhf.
__global__ __launch_bounds__(256) void score_kernel(
    const float* __restrict__ x, const float* __restrict__ W,
    const float* __restrict__ bptr, float* __restrict__ score_out,
    double* __restrict__ dot_out) {
  int wave = threadIdx.x >> 6;
  int lane = threadIdx.x & 63;
  int node = blockIdx.x * 4 + wave;
  const float4* xr = reinterpret_cast<const float4*>(x + (size_t)node * FIN);
  const float4* wr = reinterpret_cast<const float4*>(W);
  float4 xv = xr[lane];
  float4 wv = wr[lane];
  double p = (double)xv.x * (double)wv.x + (double)xv.y * (double)wv.y +
             (double)xv.z * (double)wv.z + (double)xv.w * (double)wv.w;
#pragma unroll
  for (int off = 32; off >= 1; off >>= 1) p += __shfl_xor(p, off, 64);
  if (lane == 0) {
    double z = p + (double)bptr[0];
    dot_out[node]   = z;
    score_out[node] = tanhf((float)z);   // MULTIPLIER == 1.0
  }
}

// ---------------------------------------------------------------------------
// Kernel 2 (FROZEN): per-graph hybrid bitonic sort of (f64 dot, idx).
__global__ __launch_bounds__(1024) void topk_kernel(
    const double* __restrict__ dots, float* __restrict__ perm_out,
    float* __restrict__ batch_out, int* __restrict__ node_map) {
  __shared__ double sk[N_PER];
  __shared__ int    si[N_PER];
  int b = blockIdx.x;
  int t = threadIdx.x;
  int base = b * N_PER;
  double key = dots[base + t];
  int    idx = t;
  node_map[base + t] = -1;   // block owns exactly its graph's slice
  for (int k = 2; k <= N_PER; k <<= 1) {
    for (int j = k >> 1; j > 0; j >>= 1) {
      bool lower = (t & j) == 0;
      bool dirUp = (t & k) == 0;
      double okey; int oidx;
      if (j >= 64) {
        sk[t] = key; si[t] = idx;
        __syncthreads();
        okey = sk[t ^ j]; oidx = si[t ^ j];
        __syncthreads();
      } else {
        okey = __shfl_xor(key, j, 64);
        oidx = __shfl_xor(idx, j, 64);
      }
      bool own_prec = (key > okey) || (key == okey && idx < oidx);
      bool want_prec = (lower == dirUp);
      if (own_prec != want_prec) { key = okey; idx = oidx; }
    }
  }
  if (t < KSEL) {
    int g   = base + idx;          // global node id
    int gid = b * KSEL + t;        // remapped id (rank order)
    perm_out[gid]  = (float)g;
    batch_out[gid] = (float)b;
    node_map[g]    = gid;
  }
}

// ---------------------------------------------------------------------------
// Kernel 3 (FROZEN): x_out[r] = x[perm[r]] * score[perm[r]].
__global__ __launch_bounds__(256) void gather_kernel(
    const float* __restrict__ x, const float* __restrict__ perm_f,
    const float* __restrict__ score, float* __restrict__ xout) {
  int wave = threadIdx.x >> 6;
  int lane = threadIdx.x & 63;
  int r = blockIdx.x * 4 + wave;
  int g = (int)perm_f[r];           // exact (<= 65535)
  float s = score[g];
  float4 v = reinterpret_cast<const float4*>(x + (size_t)g * FIN)[lane];
  float4 o;
  o.x = v.x * s; o.y = v.y * s; o.z = v.z * s; o.w = v.w * s;
  reinterpret_cast<float4*>(xout + (size_t)r * FIN)[lane] = o;
}

// ---------------------------------------------------------------------------
// Kernel 4a (FROZEN): edge mask + remap, 4 edges/thread, all 16-B vector ops.
__global__ __launch_bounds__(256) void edgeA_kernel(
    const int* __restrict__ ei, const int* __restrict__ node_map,
    float* __restrict__ ei_out, float* __restrict__ emask_out) {
  int t = blockIdx.x * 256 + threadIdx.x;   // handles edges 4t..4t+3
  int4 r4 = reinterpret_cast<const int4*>(ei)[t];
  int4 c4 = reinterpret_cast<const int4*>(ei + EDG)[t];
  int nr0 = node_map[r4.x], nr1 = node_map[r4.y];
  int nr2 = node_map[r4.z], nr3 = node_map[r4.w];
  int nc0 = node_map[c4.x], nc1 = node_map[c4.y];
  int nc2 = node_map[c4.z], nc3 = node_map[c4.w];
  bool m0 = (nr0 >= 0) && (nc0 >= 0);
  bool m1 = (nr1 >= 0) && (nc1 >= 0);
  bool m2 = (nr2 >= 0) && (nc2 >= 0);
  bool m3 = (nr3 >= 0) && (nc3 >= 0);
  float4 ro = make_float4(m0 ? (float)nr0 : -1.0f, m1 ? (float)nr1 : -1.0f,
                          m2 ? (float)nr2 : -1.0f, m3 ? (float)nr3 : -1.0f);
  float4 co = make_float4(m0 ? (float)nc0 : -1.0f, m1 ? (float)nc1 : -1.0f,
                          m2 ? (float)nc2 : -1.0f, m3 ? (float)nc3 : -1.0f);
  float4 mo = make_float4(m0 ? 1.0f : 0.0f, m1 ? 1.0f : 0.0f,
                          m2 ? 1.0f : 0.0f, m3 ? 1.0f : 0.0f);
  reinterpret_cast<float4*>(ei_out)[t]       = ro;
  reinterpret_cast<float4*>(ei_out + EDG)[t] = co;
  reinterpret_cast<float4*>(emask_out)[t]    = mo;
}

// ---------------------------------------------------------------------------
// Kernel 4b (FROZEN): ea_new = emask ? edge_attr : 0; 8 float4 slots/thread.
__global__ __launch_bounds__(256) void edgeB_kernel(
    const float* __restrict__ ea, const float* __restrict__ emask,
    float* __restrict__ ea_out) {
  int t = threadIdx.x;
  int f0 = blockIdx.x * 2048;     // block covers float4 units [f0, f0+2048)
  const float4* ea4 = reinterpret_cast<const float4*>(ea);
  float4*      out4 = reinterpret_cast<float4*>(ea_out);
  float mm[8];
#pragma unroll
  for (int q = 0; q < 8; ++q) {
    int fi = f0 + q * 256 + t;
    mm[q] = emask[fi >> 2];
  }
  float4 v[8];
#pragma unroll
  for (int q = 0; q < 8; ++q) {
    int fi = f0 + q * 256 + t;
    v[q] = make_float4(0.f, 0.f, 0.f, 0.f);
    if (mm[q] != 0.0f) v[q] = ea4[fi];
  }
#pragma unroll
  for (int q = 0; q < 8; ++q) {
    int fi = f0 + q * 256 + t;
    out4[fi] = v[q];
  }
}

// ---------------------------------------------------------------------------
extern "C" void kernel_launch(void* const* d_in, const int* in_sizes, int n_in,
                              void* d_out, int out_size, void* d_ws, size_t ws_size,
                              hipStream_t stream) {
  const float* x  = (const float*)d_in[0];
  const int*   ei = (const int*)d_in[1];
  const float* ea = (const float*)d_in[2];
  // d_in[3] = batch (unused: graphs contiguous & equal size)
  const float* W  = (const float*)d_in[4];
  const float* bb = (const float*)d_in[5];

  float* out       = (float*)d_out;
  float* xout      = out + OFF_XOUT;
  float* ei_out    = out + OFF_EI;
  float* ea_out    = out + OFF_EA;
  float* batch_out = out + OFF_BATCH;
  float* perm_out  = out + OFF_PERM;
  float* score_out = out + OFF_SCORE;
  float* emask_out = out + OFF_EMASK;

  int*    node_map = (int*)d_ws;                          // 256 KB
  double* dots     = (double*)((int*)d_ws + WS_DOTS_OFF); // 512 KB @ +256KB

  score_kernel <<<NTOT / 4, 256, 0, stream>>>(x, W, bb, score_out, dots);
  topk_kernel  <<<BGRAPH, 1024, 0, stream>>>(dots, perm_out, batch_out, node_map);
  gather_kernel<<<(BGRAPH * KSEL) / 4, 256, 0, stream>>>(x, perm_out, score_out, xout);

  // Edge pair x5 (idempotent, production-ordered A->B pairs).
  // R9 - R7 = 4*(a+b) + 8c. Passes 2-5 are cache-warm (read: known bias).
  for (int rep = 0; rep < 5; ++rep) {
    edgeA_kernel <<<EDG / 4 / 256, 256, 0, stream>>>(ei, node_map, ei_out, emask_out);
    edgeB_kernel <<<(EDG * 4) / 2048, 256, 0, stream>>>(ea, emask_out, ea_out);
  }
}

// Round 10
// 108.460 us; speedup vs baseline: 2.9559x; 2.9559x over previous
//
#include <hip/hip_runtime.h>
#include <math.h>

// Problem constants (match reference)
#define BGRAPH 64
#define N_PER  1024
#define KSEL   512
#define NTOT   65536       // BGRAPH * N_PER
#define EDG    2097152
#define FIN    256
#define FE     16

// d_out flat layout (float32 elements), reference tuple order:
#define OFF_XOUT   0
#define OFF_EI     8388608
#define OFF_EA     12582912
#define OFF_BATCH  46137344
#define OFF_PERM   46170112
#define OFF_SCORE  46202880
#define OFF_EMASK  46268416

// d_ws layout: [0,256KB) node_map (int[65536]); [256KB,768KB) dots (double[65536])
#define WS_DOTS_OFF 65536   // in ints

// ---------------------------------------------------------------------------
// Kernel 1 (FROZEN, absmax 128 over 8 passes): z = dot(x,W)+b in f64 rank
// key; value output via monotone-equivalent f32 tanhf.
__global__ __launch_bounds__(256) void score_kernel(
    const float* __restrict__ x, const float* __restrict__ W,
    const float* __restrict__ bptr, float* __restrict__ score_out,
    double* __restrict__ dot_out) {
  int wave = threadIdx.x >> 6;
  int lane = threadIdx.x & 63;
  int node = blockIdx.x * 4 + wave;
  const float4* xr = reinterpret_cast<const float4*>(x + (size_t)node * FIN);
  const float4* wr = reinterpret_cast<const float4*>(W);
  float4 xv = xr[lane];
  float4 wv = wr[lane];
  double p = (double)xv.x * (double)wv.x + (double)xv.y * (double)wv.y +
             (double)xv.z * (double)wv.z + (double)xv.w * (double)wv.w;
#pragma unroll
  for (int off = 32; off >= 1; off >>= 1) p += __shfl_xor(p, off, 64);
  if (lane == 0) {
    double z = p + (double)bptr[0];
    dot_out[node]   = z;
    score_out[node] = tanhf((float)z);   // MULTIPLIER == 1.0
  }
}

// ---------------------------------------------------------------------------
// Kernel 2 (FROZEN): per-graph hybrid bitonic sort of (f64 dot, idx).
// j<=32 via __shfl_xor (no barrier), j>=64 via LDS. Desc key, ties idx-asc.
__global__ __launch_bounds__(1024) void topk_kernel(
    const double* __restrict__ dots, float* __restrict__ perm_out,
    float* __restrict__ batch_out, int* __restrict__ node_map) {
  __shared__ double sk[N_PER];
  __shared__ int    si[N_PER];
  int b = blockIdx.x;
  int t = threadIdx.x;
  int base = b * N_PER;
  double key = dots[base + t];
  int    idx = t;
  node_map[base + t] = -1;   // block owns exactly its graph's slice
  for (int k = 2; k <= N_PER; k <<= 1) {
    for (int j = k >> 1; j > 0; j >>= 1) {
      bool lower = (t & j) == 0;
      bool dirUp = (t & k) == 0;
      double okey; int oidx;
      if (j >= 64) {
        sk[t] = key; si[t] = idx;
        __syncthreads();
        okey = sk[t ^ j]; oidx = si[t ^ j];
        __syncthreads();
      } else {
        okey = __shfl_xor(key, j, 64);
        oidx = __shfl_xor(idx, j, 64);
      }
      bool own_prec = (key > okey) || (key == okey && idx < oidx);
      bool want_prec = (lower == dirUp);
      if (own_prec != want_prec) { key = okey; idx = oidx; }
    }
  }
  if (t < KSEL) {
    int g   = base + idx;          // global node id
    int gid = b * KSEL + t;        // remapped id (rank order)
    perm_out[gid]  = (float)g;
    batch_out[gid] = (float)b;
    node_map[g]    = gid;
  }
}

// ---------------------------------------------------------------------------
// Kernel 3 (FROZEN): x_out[r] = x[perm[r]] * score[perm[r]]. One wave per
// row; runs right after topk so x is still L3-resident from score's pass.
__global__ __launch_bounds__(256) void gather_kernel(
    const float* __restrict__ x, const float* __restrict__ perm_f,
    const float* __restrict__ score, float* __restrict__ xout) {
  int wave = threadIdx.x >> 6;
  int lane = threadIdx.x & 63;
  int r = blockIdx.x * 4 + wave;
  int g = (int)perm_f[r];           // exact (<= 65535)
  float s = score[g];
  float4 v = reinterpret_cast<const float4*>(x + (size_t)g * FIN)[lane];
  float4 o;
  o.x = v.x * s; o.y = v.y * s; o.z = v.z * s; o.w = v.w * s;
  reinterpret_cast<float4*>(xout + (size_t)r * FIN)[lane] = o;
}

// ---------------------------------------------------------------------------
// Kernel 4 (merged edgeA+edgeB, R10): block owns 1024 edges.
// Phase 1 == R7 edgeA (verified): 4 edges/thread, int4 ei loads, 8 node_map
//   gathers (L2-resident 256 KB ws), float4 ei_out/emask stores. Mask also
//   dropped into 4 KB LDS.
// Phase 2 == R7 edgeB (verified): 16 fully-coalesced float4 iterations over
//   edge_attr; read predicated by mask from LDS (4-lane broadcast,
//   conflict-free; ~75% of the 128 MB read skipped); store unconditional
//   (poisoned output buffer must get zeros).
// vs R7 split: kills the 8 MB emask global re-read, one launch, and one
// full-pipeline drain between A and B.
__global__ __launch_bounds__(256) void edge_kernel(
    const int* __restrict__ ei, const int* __restrict__ node_map,
    const float* __restrict__ ea, float* __restrict__ ei_out,
    float* __restrict__ emask_out, float* __restrict__ ea_out) {
  __shared__ float smask[1024];
  int t  = threadIdx.x;
  int e0 = blockIdx.x * 1024;          // edges [e0, e0+1024)
  int ft = blockIdx.x * 256 + t;       // int4/float4 unit index for phase 1

  int4 r4 = reinterpret_cast<const int4*>(ei)[ft];
  int4 c4 = reinterpret_cast<const int4*>(ei + EDG)[ft];
  int nr0 = node_map[r4.x], nr1 = node_map[r4.y];
  int nr2 = node_map[r4.z], nr3 = node_map[r4.w];
  int nc0 = node_map[c4.x], nc1 = node_map[c4.y];
  int nc2 = node_map[c4.z], nc3 = node_map[c4.w];
  bool m0 = (nr0 >= 0) && (nc0 >= 0);
  bool m1 = (nr1 >= 0) && (nc1 >= 0);
  bool m2 = (nr2 >= 0) && (nc2 >= 0);
  bool m3 = (nr3 >= 0) && (nc3 >= 0);
  float4 ro = make_float4(m0 ? (float)nr0 : -1.0f, m1 ? (float)nr1 : -1.0f,
                          m2 ? (float)nr2 : -1.0f, m3 ? (float)nr3 : -1.0f);
  float4 co = make_float4(m0 ? (float)nc0 : -1.0f, m1 ? (float)nc1 : -1.0f,
                          m2 ? (float)nc2 : -1.0f, m3 ? (float)nc3 : -1.0f);
  float4 mo = make_float4(m0 ? 1.0f : 0.0f, m1 ? 1.0f : 0.0f,
                          m2 ? 1.0f : 0.0f, m3 ? 1.0f : 0.0f);
  reinterpret_cast<float4*>(ei_out)[ft]       = ro;
  reinterpret_cast<float4*>(ei_out + EDG)[ft] = co;
  reinterpret_cast<float4*>(emask_out)[ft]    = mo;
  reinterpret_cast<float4*>(smask)[t]         = mo;
  __syncthreads();

  const float4* ea4 = reinterpret_cast<const float4*>(ea) + (size_t)e0 * 4;
  float4*      out4 = reinterpret_cast<float4*>(ea_out)   + (size_t)e0 * 4;
#pragma unroll
  for (int q = 0; q < 16; ++q) {
    int fi = q * 256 + t;                 // local float4 index in [0,4096)
    float mm = smask[fi >> 2];
    float4 v = make_float4(0.f, 0.f, 0.f, 0.f);
    if (mm != 0.0f) v = ea4[fi];
    out4[fi] = v;
  }
}

// ---------------------------------------------------------------------------
extern "C" void kernel_launch(void* const* d_in, const int* in_sizes, int n_in,
                              void* d_out, int out_size, void* d_ws, size_t ws_size,
                              hipStream_t stream) {
  const float* x  = (const float*)d_in[0];
  const int*   ei = (const int*)d_in[1];
  const float* ea = (const float*)d_in[2];
  // d_in[3] = batch (unused: graphs contiguous & equal size)
  const float* W  = (const float*)d_in[4];
  const float* bb = (const float*)d_in[5];

  float* out       = (float*)d_out;
  float* xout      = out + OFF_XOUT;
  float* ei_out    = out + OFF_EI;
  float* ea_out    = out + OFF_EA;
  float* batch_out = out + OFF_BATCH;
  float* perm_out  = out + OFF_PERM;
  float* score_out = out + OFF_SCORE;
  float* emask_out = out + OFF_EMASK;

  int*    node_map = (int*)d_ws;                          // 256 KB
  double* dots     = (double*)((int*)d_ws + WS_DOTS_OFF); // 512 KB @ +256KB

  score_kernel <<<NTOT / 4, 256, 0, stream>>>(x, W, bb, score_out, dots);
  topk_kernel  <<<BGRAPH, 1024, 0, stream>>>(dots, perm_out, batch_out, node_map);
  gather_kernel<<<(BGRAPH * KSEL) / 4, 256, 0, stream>>>(x, perm_out, score_out, xout);
  edge_kernel  <<<EDG / 1024, 256, 0, stream>>>(ei, node_map, ea, ei_out, emask_out, ea_out);
}

// Round 11
// 107.920 us; speedup vs baseline: 2.9707x; 1.0050x over previous
//
#include <hip/hip_runtime.h>
#include <math.h>

// Problem constants (match reference)
#define BGRAPH 64
#define N_PER  1024
#define KSEL   512
#define NTOT   65536       // BGRAPH * N_PER
#define EDG    2097152
#define FIN    256
#define FE     16

// d_out flat layout (float32 elements), reference tuple order:
#define OFF_XOUT   0
#define OFF_EI     8388608
#define OFF_EA     12582912
#define OFF_BATCH  46137344
#define OFF_PERM   46170112
#define OFF_SCORE  46202880
#define OFF_EMASK  46268416

// d_ws layout: [0,256KB) node_map (int[65536]); [256KB,768KB) dots (double[65536])
#define WS_DOTS_OFF 65536   // in ints

#define GATHER_BLOCKS 8192   // (BGRAPH*KSEL)/4 rows, 4 rows/block
#define EDGE_BLOCKS   2048   // EDG/1024 edges, 1024 edges/block

// ---------------------------------------------------------------------------
// Kernel 1 (FROZEN, absmax 128 over 9 passes): z = dot(x,W)+b in f64 rank
// key; value output via monotone-equivalent f32 tanhf.
__global__ __launch_bounds__(256) void score_kernel(
    const float* __restrict__ x, const float* __restrict__ W,
    const float* __restrict__ bptr, float* __restrict__ score_out,
    double* __restrict__ dot_out) {
  int wave = threadIdx.x >> 6;
  int lane = threadIdx.x & 63;
  int node = blockIdx.x * 4 + wave;
  const float4* xr = reinterpret_cast<const float4*>(x + (size_t)node * FIN);
  const float4* wr = reinterpret_cast<const float4*>(W);
  float4 xv = xr[lane];
  float4 wv = wr[lane];
  double p = (double)xv.x * (double)wv.x + (double)xv.y * (double)wv.y +
             (double)xv.z * (double)wv.z + (double)xv.w * (double)wv.w;
#pragma unroll
  for (int off = 32; off >= 1; off >>= 1) p += __shfl_xor(p, off, 64);
  if (lane == 0) {
    double z = p + (double)bptr[0];
    dot_out[node]   = z;
    score_out[node] = tanhf((float)z);   // MULTIPLIER == 1.0
  }
}

// ---------------------------------------------------------------------------
// Kernel 2 (FROZEN): per-graph hybrid bitonic sort of (f64 dot, idx).
// j<=32 via __shfl_xor (no barrier), j>=64 via LDS. Desc key, ties idx-asc.
__global__ __launch_bounds__(1024) void topk_kernel(
    const double* __restrict__ dots, float* __restrict__ perm_out,
    float* __restrict__ batch_out, int* __restrict__ node_map) {
  __shared__ double sk[N_PER];
  __shared__ int    si[N_PER];
  int b = blockIdx.x;
  int t = threadIdx.x;
  int base = b * N_PER;
  double key = dots[base + t];
  int    idx = t;
  node_map[base + t] = -1;   // block owns exactly its graph's slice
  for (int k = 2; k <= N_PER; k <<= 1) {
    for (int j = k >> 1; j > 0; j >>= 1) {
      bool lower = (t & j) == 0;
      bool dirUp = (t & k) == 0;
      double okey; int oidx;
      if (j >= 64) {
        sk[t] = key; si[t] = idx;
        __syncthreads();
        okey = sk[t ^ j]; oidx = si[t ^ j];
        __syncthreads();
      } else {
        okey = __shfl_xor(key, j, 64);
        oidx = __shfl_xor(idx, j, 64);
      }
      bool own_prec = (key > okey) || (key == okey && idx < oidx);
      bool want_prec = (lower == dirUp);
      if (own_prec != want_prec) { key = okey; idx = oidx; }
    }
  }
  if (t < KSEL) {
    int g   = base + idx;          // global node id
    int gid = b * KSEL + t;        // remapped id (rank order)
    perm_out[gid]  = (float)g;
    batch_out[gid] = (float)b;
    node_map[g]    = gid;
  }
}

// ---------------------------------------------------------------------------
// Kernel 3 (R11): gather + edge fused by BLOCK RANGE (not interleaved — R5's
// interleave regressed). Bodies are bit-identical to the verified R10 code.
// Gather blocks come FIRST: x is still L3-resident from score's pass, and
// edge's 128-MB ea stream would evict it. Edge blocks ramp while gather
// drains — removes one full kernel boundary (~3-4 us).
__global__ __launch_bounds__(256) void tail_kernel(
    const float* __restrict__ x, const float* __restrict__ perm_f,
    const float* __restrict__ score, float* __restrict__ xout,
    const int* __restrict__ ei, const int* __restrict__ node_map,
    const float* __restrict__ ea, float* __restrict__ ei_out,
    float* __restrict__ emask_out, float* __restrict__ ea_out) {
  __shared__ float smask[1024];
  int t = threadIdx.x;

  if (blockIdx.x < GATHER_BLOCKS) {
    // ---- gather: 4 rows of x_out (== R10 gather_kernel body) ----
    int wave = t >> 6;
    int lane = t & 63;
    int r = blockIdx.x * 4 + wave;
    int g = (int)perm_f[r];           // exact (<= 65535)
    float s = score[g];
    float4 v = reinterpret_cast<const float4*>(x + (size_t)g * FIN)[lane];
    float4 o;
    o.x = v.x * s; o.y = v.y * s; o.z = v.z * s; o.w = v.w * s;
    reinterpret_cast<float4*>(xout + (size_t)r * FIN)[lane] = o;
    return;
  }

  // ---- edge: 1024 edges (== R10 edge_kernel body) ----
  int bid = blockIdx.x - GATHER_BLOCKS;
  int e0 = bid * 1024;                 // edges [e0, e0+1024)
  int ft = bid * 256 + t;              // int4/float4 unit index for phase 1

  int4 r4 = reinterpret_cast<const int4*>(ei)[ft];
  int4 c4 = reinterpret_cast<const int4*>(ei + EDG)[ft];
  int nr0 = node_map[r4.x], nr1 = node_map[r4.y];
  int nr2 = node_map[r4.z], nr3 = node_map[r4.w];
  int nc0 = node_map[c4.x], nc1 = node_map[c4.y];
  int nc2 = node_map[c4.z], nc3 = node_map[c4.w];
  bool m0 = (nr0 >= 0) && (nc0 >= 0);
  bool m1 = (nr1 >= 0) && (nc1 >= 0);
  bool m2 = (nr2 >= 0) && (nc2 >= 0);
  bool m3 = (nr3 >= 0) && (nc3 >= 0);
  float4 ro = make_float4(m0 ? (float)nr0 : -1.0f, m1 ? (float)nr1 : -1.0f,
                          m2 ? (float)nr2 : -1.0f, m3 ? (float)nr3 : -1.0f);
  float4 co = make_float4(m0 ? (float)nc0 : -1.0f, m1 ? (float)nc1 : -1.0f,
                          m2 ? (float)nc2 : -1.0f, m3 ? (float)nc3 : -1.0f);
  float4 mo = make_float4(m0 ? 1.0f : 0.0f, m1 ? 1.0f : 0.0f,
                          m2 ? 1.0f : 0.0f, m3 ? 1.0f : 0.0f);
  reinterpret_cast<float4*>(ei_out)[ft]       = ro;
  reinterpret_cast<float4*>(ei_out + EDG)[ft] = co;
  reinterpret_cast<float4*>(emask_out)[ft]    = mo;
  reinterpret_cast<float4*>(smask)[t]         = mo;
  __syncthreads();

  const float4* ea4 = reinterpret_cast<const float4*>(ea) + (size_t)e0 * 4;
  float4*      out4 = reinterpret_cast<float4*>(ea_out)   + (size_t)e0 * 4;
#pragma unroll
  for (int q = 0; q < 16; ++q) {
    int fi = q * 256 + t;                 // local float4 index in [0,4096)
    float mm = smask[fi >> 2];
    float4 v = make_float4(0.f, 0.f, 0.f, 0.f);
    if (mm != 0.0f) v = ea4[fi];
    out4[fi] = v;
  }
}

// ---------------------------------------------------------------------------
extern "C" void kernel_launch(void* const* d_in, const int* in_sizes, int n_in,
                              void* d_out, int out_size, void* d_ws, size_t ws_size,
                              hipStream_t stream) {
  const float* x  = (const float*)d_in[0];
  const int*   ei = (const int*)d_in[1];
  const float* ea = (const float*)d_in[2];
  // d_in[3] = batch (unused: graphs contiguous & equal size)
  const float* W  = (const float*)d_in[4];
  const float* bb = (const float*)d_in[5];

  float* out       = (float*)d_out;
  float* xout      = out + OFF_XOUT;
  float* ei_out    = out + OFF_EI;
  float* ea_out    = out + OFF_EA;
  float* batch_out = out + OFF_BATCH;
  float* perm_out  = out + OFF_PERM;
  float* score_out = out + OFF_SCORE;
  float* emask_out = out + OFF_EMASK;

  int*    node_map = (int*)d_ws;                          // 256 KB
  double* dots     = (double*)((int*)d_ws + WS_DOTS_OFF); // 512 KB @ +256KB

  score_kernel <<<NTOT / 4, 256, 0, stream>>>(x, W, bb, score_out, dots);
  topk_kernel  <<<BGRAPH, 1024, 0, stream>>>(dots, perm_out, batch_out, node_map);
  tail_kernel  <<<GATHER_BLOCKS + EDGE_BLOCKS, 256, 0, stream>>>(
      x, perm_out, score_out, xout, ei, node_map, ea, ei_out, emask_out, ea_out);
}

// Round 12
// 102.910 us; speedup vs baseline: 3.1153x; 1.0487x over previous
//
#include <hip/hip_runtime.h>
#include <math.h>

// Problem constants (match reference)
#define BGRAPH 64
#define N_PER  1024
#define KSEL   512
#define NTOT   65536       // BGRAPH * N_PER
#define EDG    2097152
#define FIN    256
#define FE     16

// d_out flat layout (float32 elements), reference tuple order:
#define OFF_XOUT   0
#define OFF_EI     8388608
#define OFF_EA     12582912
#define OFF_BATCH  46137344
#define OFF_PERM   46170112
#define OFF_SCORE  46202880
#define OFF_EMASK  46268416

// d_ws layout: [0,256KB) node_map (int[65536]); [256KB,768KB) dots (double[65536])
#define WS_DOTS_OFF 65536   // in ints

#define GATHER_BLOCKS 8192   // (BGRAPH*KSEL)/4 rows, 4 rows/block
#define EDGE_BLOCKS   2048   // EDG/1024 edges, 1024 edges/block

// ---------------------------------------------------------------------------
// Kernel 1 (R12 quad-row rewrite): z = dot(x,W)+b in f64 rank key; value via
// monotone-equivalent f32 tanhf. Each WAVE handles 4 rows (16 lanes/row,
// 4 float4 loads/lane): ~3x fewer issue slots per row than wave-per-row
// (shuffle tree 4 rounds per 4 rows vs 6 per row; tanh amortized; 8
// independent loads/lane for MLP). Coalescing unchanged: one load instr
// still touches 16 x 64B sectors.
// NOTE absmax=128 across all passing rounds is the bf16-compare ulp of
// 32768-scale ints in ei_new (noise floor), NOT a rank discrepancy; the f64
// tree reshape here re-rolls only ~1e-13 sum diffs (P(flip) ~3e-7).
__global__ __launch_bounds__(256) void score_kernel(
    const float* __restrict__ x, const float* __restrict__ W,
    const float* __restrict__ bptr, float* __restrict__ score_out,
    double* __restrict__ dot_out) {
  int wave = threadIdx.x >> 6;
  int lane = threadIdx.x & 63;
  int sub  = lane >> 4;            // which of the wave's 4 rows
  int l16  = lane & 15;            // lane within the 16-lane row group
  int row  = (blockIdx.x * 4 + wave) * 4 + sub;
  const float4* xr = reinterpret_cast<const float4*>(x + (size_t)row * FIN);
  const float4* wr = reinterpret_cast<const float4*>(W);   // 1 KB, L1-hot
  double p = 0.0;
#pragma unroll
  for (int q = 0; q < 4; ++q) {
    float4 xv = xr[q * 16 + l16];
    float4 wv = wr[q * 16 + l16];
    p += (double)xv.x * (double)wv.x + (double)xv.y * (double)wv.y +
         (double)xv.z * (double)wv.z + (double)xv.w * (double)wv.w;
  }
#pragma unroll
  for (int off = 8; off >= 1; off >>= 1) p += __shfl_xor(p, off, 64);
  if (l16 == 0) {
    double z = p + (double)bptr[0];
    dot_out[row]   = z;
    score_out[row] = tanhf((float)z);   // MULTIPLIER == 1.0
  }
}

// ---------------------------------------------------------------------------
// Kernel 2 (FROZEN): per-graph hybrid bitonic sort of (f64 dot, idx).
// j<=32 via __shfl_xor (no barrier), j>=64 via LDS. Desc key, ties idx-asc.
__global__ __launch_bounds__(1024) void topk_kernel(
    const double* __restrict__ dots, float* __restrict__ perm_out,
    float* __restrict__ batch_out, int* __restrict__ node_map) {
  __shared__ double sk[N_PER];
  __shared__ int    si[N_PER];
  int b = blockIdx.x;
  int t = threadIdx.x;
  int base = b * N_PER;
  double key = dots[base + t];
  int    idx = t;
  node_map[base + t] = -1;   // block owns exactly its graph's slice
  for (int k = 2; k <= N_PER; k <<= 1) {
    for (int j = k >> 1; j > 0; j >>= 1) {
      bool lower = (t & j) == 0;
      bool dirUp = (t & k) == 0;
      double okey; int oidx;
      if (j >= 64) {
        sk[t] = key; si[t] = idx;
        __syncthreads();
        okey = sk[t ^ j]; oidx = si[t ^ j];
        __syncthreads();
      } else {
        okey = __shfl_xor(key, j, 64);
        oidx = __shfl_xor(idx, j, 64);
      }
      bool own_prec = (key > okey) || (key == okey && idx < oidx);
      bool want_prec = (lower == dirUp);
      if (own_prec != want_prec) { key = okey; idx = oidx; }
    }
  }
  if (t < KSEL) {
    int g   = base + idx;          // global node id
    int gid = b * KSEL + t;        // remapped id (rank order)
    perm_out[gid]  = (float)g;
    batch_out[gid] = (float)b;
    node_map[g]    = gid;
  }
}

// ---------------------------------------------------------------------------
// Kernel 3 (FROZEN from R11): gather + edge fused by block range.
// Gather blocks first (x still L3-hot from score); edge blocks ramp while
// gather drains. Bodies identical to the verified R10 code.
__global__ __launch_bounds__(256) void tail_kernel(
    const float* __restrict__ x, const float* __restrict__ perm_f,
    const float* __restrict__ score, float* __restrict__ xout,
    const int* __restrict__ ei, const int* __restrict__ node_map,
    const float* __restrict__ ea, float* __restrict__ ei_out,
    float* __restrict__ emask_out, float* __restrict__ ea_out) {
  __shared__ float smask[1024];
  int t = threadIdx.x;

  if (blockIdx.x < GATHER_BLOCKS) {
    // ---- gather: 4 rows of x_out ----
    int wave = t >> 6;
    int lane = t & 63;
    int r = blockIdx.x * 4 + wave;
    int g = (int)perm_f[r];           // exact (<= 65535)
    float s = score[g];
    float4 v = reinterpret_cast<const float4*>(x + (size_t)g * FIN)[lane];
    float4 o;
    o.x = v.x * s; o.y = v.y * s; o.z = v.z * s; o.w = v.w * s;
    reinterpret_cast<float4*>(xout + (size_t)r * FIN)[lane] = o;
    return;
  }

  // ---- edge: 1024 edges (mask/remap + attr copy) ----
  int bid = blockIdx.x - GATHER_BLOCKS;
  int e0 = bid * 1024;                 // edges [e0, e0+1024)
  int ft = bid * 256 + t;              // int4/float4 unit index for phase 1

  int4 r4 = reinterpret_cast<const int4*>(ei)[ft];
  int4 c4 = reinterpret_cast<const int4*>(ei + EDG)[ft];
  int nr0 = node_map[r4.x], nr1 = node_map[r4.y];
  int nr2 = node_map[r4.z], nr3 = node_map[r4.w];
  int nc0 = node_map[c4.x], nc1 = node_map[c4.y];
  int nc2 = node_map[c4.z], nc3 = node_map[c4.w];
  bool m0 = (nr0 >= 0) && (nc0 >= 0);
  bool m1 = (nr1 >= 0) && (nc1 >= 0);
  bool m2 = (nr2 >= 0) && (nc2 >= 0);
  bool m3 = (nr3 >= 0) && (nc3 >= 0);
  float4 ro = make_float4(m0 ? (float)nr0 : -1.0f, m1 ? (float)nr1 : -1.0f,
                          m2 ? (float)nr2 : -1.0f, m3 ? (float)nr3 : -1.0f);
  float4 co = make_float4(m0 ? (float)nc0 : -1.0f, m1 ? (float)nc1 : -1.0f,
                          m2 ? (float)nc2 : -1.0f, m3 ? (float)nc3 : -1.0f);
  float4 mo = make_float4(m0 ? 1.0f : 0.0f, m1 ? 1.0f : 0.0f,
                          m2 ? 1.0f : 0.0f, m3 ? 1.0f : 0.0f);
  reinterpret_cast<float4*>(ei_out)[ft]       = ro;
  reinterpret_cast<float4*>(ei_out + EDG)[ft] = co;
  reinterpret_cast<float4*>(emask_out)[ft]    = mo;
  reinterpret_cast<float4*>(smask)[t]         = mo;
  __syncthreads();

  const float4* ea4 = reinterpret_cast<const float4*>(ea) + (size_t)e0 * 4;
  float4*      out4 = reinterpret_cast<float4*>(ea_out)   + (size_t)e0 * 4;
#pragma unroll
  for (int q = 0; q < 16; ++q) {
    int fi = q * 256 + t;                 // local float4 index in [0,4096)
    float mm = smask[fi >> 2];
    float4 v = make_float4(0.f, 0.f, 0.f, 0.f);
    if (mm != 0.0f) v = ea4[fi];
    out4[fi] = v;
  }
}

// ---------------------------------------------------------------------------
extern "C" void kernel_launch(void* const* d_in, const int* in_sizes, int n_in,
                              void* d_out, int out_size, void* d_ws, size_t ws_size,
                              hipStream_t stream) {
  const float* x  = (const float*)d_in[0];
  const int*   ei = (const int*)d_in[1];
  const float* ea = (const float*)d_in[2];
  // d_in[3] = batch (unused: graphs contiguous & equal size)
  const float* W  = (const float*)d_in[4];
  const float* bb = (const float*)d_in[5];

  float* out       = (float*)d_out;
  float* xout      = out + OFF_XOUT;
  float* ei_out    = out + OFF_EI;
  float* ea_out    = out + OFF_EA;
  float* batch_out = out + OFF_BATCH;
  float* perm_out  = out + OFF_PERM;
  float* score_out = out + OFF_SCORE;
  float* emask_out = out + OFF_EMASK;

  int*    node_map = (int*)d_ws;                          // 256 KB
  double* dots     = (double*)((int*)d_ws + WS_DOTS_OFF); // 512 KB @ +256KB

  score_kernel <<<NTOT / 16, 256, 0, stream>>>(x, W, bb, score_out, dots);
  topk_kernel  <<<BGRAPH, 1024, 0, stream>>>(dots, perm_out, batch_out, node_map);
  tail_kernel  <<<GATHER_BLOCKS + EDGE_BLOCKS, 256, 0, stream>>>(
      x, perm_out, score_out, xout, ei, node_map, ea, ei_out, emask_out, ea_out);
}